// Round 1
// baseline (191.246 us; speedup 1.0000x reference)
//
#include <hip/hip_runtime.h>
#include <hip/hip_bf16.h>
#include <stdint.h>

// Problem constants
#define S_ROWS 8192
#define T_ROWS 8192
#define SRC 768
#define DK 128
// exp(s/sqrt(128)) = exp2(s * log2(e)/sqrt(128))
#define SCALE_LOG2E 0.12751743f

typedef __bf16 bf16x8 __attribute__((ext_vector_type(8)));
typedef float floatx4 __attribute__((ext_vector_type(4)));
typedef uint32_t u32x4v __attribute__((ext_vector_type(4)));

__device__ __forceinline__ bf16x8 load_bf8(const void* p) {
    u32x4v v = *(const u32x4v*)p;
    return __builtin_bit_cast(bf16x8, v);
}

// ---------------------------------------------------------------------------
// Kernel A: convert w_q, w_k to bf16; compute c[768] = w_o @ w_v
// grid 100 x 256
// ---------------------------------------------------------------------------
__global__ void k_prep(const float* __restrict__ w_q, const float* __restrict__ w_k,
                       const float* __restrict__ w_v, const float* __restrict__ w_o,
                       __hip_bfloat16* __restrict__ wq_bf,
                       __hip_bfloat16* __restrict__ wk_bf,
                       float* __restrict__ c_out) {
    int b = blockIdx.x;
    int t = threadIdx.x;
    if (b < 96) {
        // 96 blocks * 2048 = 196608 elements total (98304 wq + 98304 wk)
        #pragma unroll
        for (int p = 0; p < 8; ++p) {
            int i = b * 2048 + p * 256 + t;
            if (i < 98304) wq_bf[i] = __float2bfloat16(w_q[i]);
            else           wk_bf[i - 98304] = __float2bfloat16(w_k[i - 98304]);
        }
    } else {
        int j = (b - 96) * 256 + t;
        if (j < 768) {
            float acc = 0.f;
            #pragma unroll 8
            for (int k = 0; k < 64; ++k) acc += w_o[k] * w_v[k * 768 + j];
            c_out[j] = acc;
        }
    }
}

// ---------------------------------------------------------------------------
// Kernel B: Q = x1 @ w_q^T (bid 0..63), K = x2 @ w_k^T (bid 64..127), + vs
// 256 threads = 4 waves (2x2), each block computes a 128x128 output tile.
// ---------------------------------------------------------------------------
__global__ __launch_bounds__(256) void k_qk(
        const float* __restrict__ x1, const float* __restrict__ x2,
        const __hip_bfloat16* __restrict__ wq_bf,
        const __hip_bfloat16* __restrict__ wk_bf,
        const float* __restrict__ c_in,
        __hip_bfloat16* __restrict__ Qb, __hip_bfloat16* __restrict__ Kb,
        float* __restrict__ vs_g) {
    constexpr int LDA = 40;  // 32 + 8 pad, bf16 elems (row stride 80 B, 16B-mult)
    __shared__ alignas(16) __hip_bfloat16 sA[128 * LDA];
    __shared__ float sC[768];

    int bid = blockIdx.x;
    bool isK = bid >= 64;
    int row0 = (bid & 63) * 128;
    const float* x = isK ? x2 : x1;
    const __hip_bfloat16* w = isK ? wk_bf : wq_bf;
    __hip_bfloat16* outp = isK ? Kb : Qb;

    int t = threadIdx.x;
    int wave = t >> 6, lane = t & 63;
    int wr = wave >> 1, wc = wave & 1;
    int m = lane & 15, quad = lane >> 4;

    // stage c into LDS (only K-blocks use it, but stage uniformly)
    #pragma unroll
    for (int p = 0; p < 3; ++p) sC[p * 256 + t] = c_in[p * 256 + t];
    __syncthreads();

    if (isK) {
        // vs[row] = x2[row] . c ; 2 threads per row (split k), shfl combine
        int r = t >> 1, h = t & 1;
        const float* xr = x + (size_t)(row0 + r) * 768 + h * 384;
        const float* cr = &sC[h * 384];
        float acc = 0.f;
        #pragma unroll 8
        for (int j = 0; j < 384; j += 4) {
            float4 v = *(const float4*)(xr + j);
            acc += v.x * cr[j] + v.y * cr[j + 1] + v.z * cr[j + 2] + v.w * cr[j + 3];
        }
        acc += __shfl_xor(acc, 1, 64);
        if (h == 0) vs_g[row0 + r] = acc;
    }

    floatx4 acc[4][4];
    #pragma unroll
    for (int i = 0; i < 4; ++i)
        #pragma unroll
        for (int j = 0; j < 4; ++j) acc[i][j] = {0.f, 0.f, 0.f, 0.f};

    for (int kc = 0; kc < 768; kc += 32) {
        __syncthreads();
        // stage A tile: 128 rows x 32 cols f32 -> bf16 (4 float4 per thread)
        #pragma unroll
        for (int p = 0; p < 4; ++p) {
            int f = p * 256 + t;
            int r = f >> 3, c4 = (f & 7) * 4;
            float4 v = *(const float4*)(x + (size_t)(row0 + r) * 768 + kc + c4);
            __hip_bfloat16* dst = &sA[r * LDA + c4];
            dst[0] = __float2bfloat16(v.x); dst[1] = __float2bfloat16(v.y);
            dst[2] = __float2bfloat16(v.z); dst[3] = __float2bfloat16(v.w);
        }
        __syncthreads();

        bf16x8 afr[4], bfr[4];
        #pragma unroll
        for (int i = 0; i < 4; ++i)
            afr[i] = load_bf8(&sA[(wr * 64 + i * 16 + m) * LDA + quad * 8]);
        #pragma unroll
        for (int j = 0; j < 4; ++j) {
            int n = wc * 64 + j * 16 + m;
            bfr[j] = load_bf8(w + (size_t)n * 768 + kc + quad * 8);
        }
        #pragma unroll
        for (int i = 0; i < 4; ++i)
            #pragma unroll
            for (int j = 0; j < 4; ++j)
                acc[i][j] = __builtin_amdgcn_mfma_f32_16x16x32_bf16(afr[i], bfr[j], acc[i][j], 0, 0, 0);
    }

    // write C (bf16): C layout col=lane&15, row=quad*4+reg
    #pragma unroll
    for (int i = 0; i < 4; ++i)
        #pragma unroll
        for (int j = 0; j < 4; ++j)
            #pragma unroll
            for (int r = 0; r < 4; ++r) {
                int row = wr * 64 + i * 16 + quad * 4 + r;
                int col = wc * 64 + j * 16 + m;
                outp[(size_t)(row0 + row) * 128 + col] = __float2bfloat16(acc[i][j][r]);
            }
}

// ---------------------------------------------------------------------------
// Kernel C: flash-style attention row-sums.
// grid 512 = 64 q-blocks x 8 t-chunks. Block: 128 q rows x 1024 t keys.
// num[s] += sum_t exp(S)*vs[t]; den[s] += sum_t exp(S)
// ---------------------------------------------------------------------------
__global__ __launch_bounds__(256) void k_attn(
        const __hip_bfloat16* __restrict__ Qb, const __hip_bfloat16* __restrict__ Kb,
        const float* __restrict__ vs_g,
        float* __restrict__ num_g, float* __restrict__ den_g) {
    constexpr int LDQ = 136;  // 128 + 8 pad (row stride 272 B, 16B-mult)
    __shared__ alignas(16) __hip_bfloat16 sQ[128 * LDQ];
    __shared__ alignas(16) __hip_bfloat16 sK[128 * LDQ];
    __shared__ float sVS[1024];

    int bid = blockIdx.x;
    int qb = bid >> 3, tc = bid & 7;
    int q0 = qb * 128, t0 = tc * 1024;

    int t = threadIdx.x;
    int wave = t >> 6, lane = t & 63;
    int wr = wave >> 1, wc = wave & 1;
    int m = lane & 15, quad = lane >> 4;

    // load Q tile (128x128 bf16) into LDS: 2048 16B chunks, 8 per thread
    #pragma unroll
    for (int p = 0; p < 8; ++p) {
        int f = p * 256 + t;
        int r = f >> 4, c = (f & 15) * 8;
        *(u32x4v*)(&sQ[r * LDQ + c]) = *(const u32x4v*)(Qb + (size_t)(q0 + r) * 128 + c);
    }
    // load vs for this block's whole t-range
    #pragma unroll
    for (int p = 0; p < 4; ++p) sVS[p * 256 + t] = vs_g[t0 + p * 256 + t];

    float num_acc[4][4], den_acc[4][4];
    #pragma unroll
    for (int i = 0; i < 4; ++i)
        #pragma unroll
        for (int r = 0; r < 4; ++r) { num_acc[i][r] = 0.f; den_acc[i][r] = 0.f; }

    for (int it = 0; it < 8; ++it) {
        __syncthreads();
        // stage K tile (128 keys x 128 dims)
        #pragma unroll
        for (int p = 0; p < 8; ++p) {
            int f = p * 256 + t;
            int r = f >> 4, c = (f & 15) * 8;
            *(u32x4v*)(&sK[r * LDQ + c]) =
                *(const u32x4v*)(Kb + (size_t)(t0 + it * 128 + r) * 128 + c);
        }
        __syncthreads();

        floatx4 acc[4][4];
        #pragma unroll
        for (int i = 0; i < 4; ++i)
            #pragma unroll
            for (int j = 0; j < 4; ++j) acc[i][j] = {0.f, 0.f, 0.f, 0.f};

        #pragma unroll
        for (int kk = 0; kk < 4; ++kk) {
            bf16x8 afr[4], bfr[4];
            #pragma unroll
            for (int i = 0; i < 4; ++i)
                afr[i] = load_bf8(&sQ[(wr * 64 + i * 16 + m) * LDQ + kk * 32 + quad * 8]);
            #pragma unroll
            for (int j = 0; j < 4; ++j)
                bfr[j] = load_bf8(&sK[(wc * 64 + j * 16 + m) * LDQ + kk * 32 + quad * 8]);
            #pragma unroll
            for (int i = 0; i < 4; ++i)
                #pragma unroll
                for (int j = 0; j < 4; ++j)
                    acc[i][j] = __builtin_amdgcn_mfma_f32_16x16x32_bf16(afr[i], bfr[j], acc[i][j], 0, 0, 0);
        }

        // exp + accumulate per-lane partial row sums
        #pragma unroll
        for (int j = 0; j < 4; ++j) {
            float vsv = sVS[it * 128 + wc * 64 + j * 16 + m];
            #pragma unroll
            for (int i = 0; i < 4; ++i)
                #pragma unroll
                for (int r = 0; r < 4; ++r) {
                    float p = __builtin_amdgcn_exp2f(acc[i][j][r] * SCALE_LOG2E);
                    den_acc[i][r] += p;
                    num_acc[i][r] += p * vsv;
                }
        }
    }

    // reduce across the 16 lanes of each quad-group, then one atomic per row
    #pragma unroll
    for (int i = 0; i < 4; ++i)
        #pragma unroll
        for (int r = 0; r < 4; ++r) {
            float n = num_acc[i][r], d = den_acc[i][r];
            #pragma unroll
            for (int mask = 1; mask <= 8; mask <<= 1) {
                n += __shfl_xor(n, mask, 64);
                d += __shfl_xor(d, mask, 64);
            }
            if ((lane & 15) == 0) {
                int row = q0 + wr * 64 + i * 16 + quad * 4 + r;
                atomicAdd(&num_g[row], n);
                atomicAdd(&den_g[row], d);
            }
        }
}

// ---------------------------------------------------------------------------
// Kernel D: gated = x1 * (1 - num/den). float4 grid-mapped, memory-bound.
// grid 6144 x 256, one float4 per thread.
// ---------------------------------------------------------------------------
__global__ void k_final(const float* __restrict__ x1,
                        const float* __restrict__ num_g,
                        const float* __restrict__ den_g,
                        float* __restrict__ outp) {
    int idx = blockIdx.x * 256 + threadIdx.x;  // float4 index, 192 per row
    int s = idx / 192;
    float4 v = *(const float4*)(x1 + (size_t)idx * 4);
    float g = 1.0f - num_g[s] / den_g[s];
    float4 rv;
    rv.x = v.x * g; rv.y = v.y * g; rv.z = v.z * g; rv.w = v.w * g;
    *(float4*)(outp + (size_t)idx * 4) = rv;
}

// ---------------------------------------------------------------------------
extern "C" void kernel_launch(void* const* d_in, const int* in_sizes, int n_in,
                              void* d_out, int out_size, void* d_ws, size_t ws_size,
                              hipStream_t stream) {
    const float* x1  = (const float*)d_in[0];
    const float* x2  = (const float*)d_in[1];
    const float* w_q = (const float*)d_in[2];
    const float* w_k = (const float*)d_in[3];
    const float* w_v = (const float*)d_in[4];
    const float* w_o = (const float*)d_in[5];
    float* outp = (float*)d_out;

    char* ws = (char*)d_ws;
    __hip_bfloat16* wq_bf = (__hip_bfloat16*)(ws + 0);        // 196608 B
    __hip_bfloat16* wk_bf = (__hip_bfloat16*)(ws + 196608);   // 196608 B
    float* c_buf          = (float*)(ws + 393216);            // 3072 B
    __hip_bfloat16* Qb    = (__hip_bfloat16*)(ws + 396288);   // 2 MB
    __hip_bfloat16* Kb    = (__hip_bfloat16*)(ws + 2493440);  // 2 MB
    float* vs_g           = (float*)(ws + 4590592);           // 32 KB
    float* num_g          = (float*)(ws + 4623360);           // 32 KB
    float* den_g          = (float*)(ws + 4656128);           // 32 KB

    hipMemsetAsync(num_g, 0, 8192 * sizeof(float), stream);
    hipMemsetAsync(den_g, 0, 8192 * sizeof(float), stream);

    k_prep<<<100, 256, 0, stream>>>(w_q, w_k, w_v, w_o, wq_bf, wk_bf, c_buf);
    k_qk<<<128, 256, 0, stream>>>(x1, x2, wq_bf, wk_bf, c_buf, Qb, Kb, vs_g);
    k_attn<<<512, 256, 0, stream>>>(Qb, Kb, vs_g, num_g, den_g);
    k_final<<<6144, 256, 0, stream>>>(x1, num_g, den_g, outp);
}

// Round 2
// 169.426 us; speedup vs baseline: 1.1288x; 1.1288x over previous
//
#include <hip/hip_runtime.h>
#include <hip/hip_bf16.h>
#include <stdint.h>

// Problem constants
#define S_ROWS 8192
#define T_ROWS 8192
#define SRC 768
#define DK 128
// exp(s/sqrt(128)) = exp2(s * log2(e)/sqrt(128))
#define SCALE_LOG2E 0.12751743f

typedef __bf16 bf16x8 __attribute__((ext_vector_type(8)));
typedef float floatx4 __attribute__((ext_vector_type(4)));
typedef uint32_t u32x4v __attribute__((ext_vector_type(4)));

__device__ __forceinline__ bf16x8 load_bf8(const void* p) {
    u32x4v v = *(const u32x4v*)p;
    return __builtin_bit_cast(bf16x8, v);
}

__device__ __forceinline__ bf16x8 cvt8(float4 u, float4 v) {
    union { bf16x8 v8; __hip_bfloat16 h[8]; } r;
    r.h[0] = __float2bfloat16(u.x); r.h[1] = __float2bfloat16(u.y);
    r.h[2] = __float2bfloat16(u.z); r.h[3] = __float2bfloat16(u.w);
    r.h[4] = __float2bfloat16(v.x); r.h[5] = __float2bfloat16(v.y);
    r.h[6] = __float2bfloat16(v.z); r.h[7] = __float2bfloat16(v.w);
    return r.v8;
}

// ---------------------------------------------------------------------------
// Kernel A: convert w_q, w_k to bf16; compute c[768] = w_o @ w_v
// ---------------------------------------------------------------------------
__global__ void k_prep(const float* __restrict__ w_q, const float* __restrict__ w_k,
                       const float* __restrict__ w_v, const float* __restrict__ w_o,
                       __hip_bfloat16* __restrict__ wq_bf,
                       __hip_bfloat16* __restrict__ wk_bf,
                       float* __restrict__ c_out) {
    int b = blockIdx.x;
    int t = threadIdx.x;
    if (b < 96) {
        #pragma unroll
        for (int p = 0; p < 8; ++p) {
            int i = b * 2048 + p * 256 + t;
            if (i < 98304) wq_bf[i] = __float2bfloat16(w_q[i]);
            else           wk_bf[i - 98304] = __float2bfloat16(w_k[i - 98304]);
        }
    } else {
        int j = (b - 96) * 256 + t;
        if (j < 768) {
            float acc = 0.f;
            #pragma unroll 8
            for (int k = 0; k < 64; ++k) acc += w_o[k] * w_v[k * 768 + j];
            c_out[j] = acc;
        }
    }
}

// ---------------------------------------------------------------------------
// Kernel B (rewritten, LDS-free): Q = x1 @ w_q^T (bid 0..255),
// K = x2 @ w_k^T (bid 256..511), + vs for K blocks.
// Each block: 32 rows x 128 cols. Each wave: 32x32 tile, A-frags loaded
// directly from global f32 + in-register cvt; B-frags from L2-resident bf16
// weights. No LDS, no syncthreads -> deep load pipelining across K-loop.
// ---------------------------------------------------------------------------
__global__ __launch_bounds__(256) void k_qk(
        const float* __restrict__ x1, const float* __restrict__ x2,
        const __hip_bfloat16* __restrict__ wq_bf,
        const __hip_bfloat16* __restrict__ wk_bf,
        const float* __restrict__ c_in,
        __hip_bfloat16* __restrict__ Qb, __hip_bfloat16* __restrict__ Kb,
        float* __restrict__ vs_g) {
    int bid = blockIdx.x;
    bool isK = bid >= 256;
    int row0 = (bid & 255) * 32;
    const float* x = isK ? x2 : x1;
    const __hip_bfloat16* w = isK ? wk_bf : wq_bf;
    __hip_bfloat16* outp = isK ? Kb : Qb;

    int t = threadIdx.x;
    int wave = t >> 6, lane = t & 63;
    int col0 = wave * 32;
    int m = lane & 15, quad = lane >> 4;

    floatx4 acc[2][2];
    #pragma unroll
    for (int i = 0; i < 2; ++i)
        #pragma unroll
        for (int j = 0; j < 2; ++j) acc[i][j] = {0.f, 0.f, 0.f, 0.f};

    const float* arow = x + (size_t)(row0 + m) * 768 + quad * 8;
    const __hip_bfloat16* brow = w + (size_t)(col0 + m) * 768 + quad * 8;

    #pragma unroll 4
    for (int kc = 0; kc < 768; kc += 32) {
        bf16x8 a[2], b[2];
        #pragma unroll
        for (int i = 0; i < 2; ++i) {
            const float* p = arow + i * 16 * 768 + kc;
            float4 u = *(const float4*)p;
            float4 v = *(const float4*)(p + 4);
            a[i] = cvt8(u, v);
        }
        #pragma unroll
        for (int j = 0; j < 2; ++j)
            b[j] = load_bf8(brow + j * 16 * 768 + kc);
        #pragma unroll
        for (int i = 0; i < 2; ++i)
            #pragma unroll
            for (int j = 0; j < 2; ++j)
                acc[i][j] = __builtin_amdgcn_mfma_f32_16x16x32_bf16(a[i], b[j], acc[i][j], 0, 0, 0);
    }

    // vs[row] = x2[row] . c for K blocks: 8 threads per row
    if (isK) {
        int r = t >> 3, h = t & 7;  // h == lane & 7
        const float* xr = x + (size_t)(row0 + r) * 768 + h * 96;
        const float* cr = c_in + h * 96;
        float vacc = 0.f;
        #pragma unroll 6
        for (int j = 0; j < 96; j += 4) {
            float4 v = *(const float4*)(xr + j);
            vacc += v.x * cr[j] + v.y * cr[j + 1] + v.z * cr[j + 2] + v.w * cr[j + 3];
        }
        vacc += __shfl_xor(vacc, 1, 64);
        vacc += __shfl_xor(vacc, 2, 64);
        vacc += __shfl_xor(vacc, 4, 64);
        if (h == 0) vs_g[row0 + r] = vacc;
    }

    // write C (bf16): C layout col=lane&15, row=quad*4+reg
    #pragma unroll
    for (int i = 0; i < 2; ++i)
        #pragma unroll
        for (int j = 0; j < 2; ++j)
            #pragma unroll
            for (int r = 0; r < 4; ++r) {
                int row = row0 + i * 16 + quad * 4 + r;
                int col = col0 + j * 16 + m;
                outp[(size_t)row * 128 + col] = __float2bfloat16(acc[i][j][r]);
            }
}

// ---------------------------------------------------------------------------
// Kernel C: flash-style attention row-sums, with register prefetch of the
// next K tile so global latency overlaps MFMA+exp of the current tile.
// grid 512 = 64 q-blocks x 8 t-chunks. Block: 128 q rows x 1024 t keys.
// ---------------------------------------------------------------------------
__global__ __launch_bounds__(256) void k_attn(
        const __hip_bfloat16* __restrict__ Qb, const __hip_bfloat16* __restrict__ Kb,
        const float* __restrict__ vs_g,
        float* __restrict__ num_g, float* __restrict__ den_g) {
    constexpr int LDQ = 136;  // 128 + 8 pad (row stride 272 B)
    __shared__ alignas(16) __hip_bfloat16 sQ[128 * LDQ];
    __shared__ alignas(16) __hip_bfloat16 sK[128 * LDQ];
    __shared__ float sVS[1024];

    int bid = blockIdx.x;
    int qb = bid >> 3, tc = bid & 7;
    int q0 = qb * 128, t0 = tc * 1024;

    int t = threadIdx.x;
    int wave = t >> 6, lane = t & 63;
    int wr = wave >> 1, wc = wave & 1;
    int m = lane & 15, quad = lane >> 4;

    // each thread owns 8 16B-chunks of a tile: chunk f -> row f>>4, col (f&15)*8
    int r_st = (t * 8) >> 4;        // rows for p-th chunk: r_st + p*... (see loop)
    // load Q tile (128x128 bf16) into LDS
    #pragma unroll
    for (int p = 0; p < 8; ++p) {
        int f = p * 256 + t;
        int r = f >> 4, c = (f & 15) * 8;
        *(u32x4v*)(&sQ[r * LDQ + c]) = *(const u32x4v*)(Qb + (size_t)(q0 + r) * 128 + c);
    }
    #pragma unroll
    for (int p = 0; p < 4; ++p) sVS[p * 256 + t] = vs_g[t0 + p * 256 + t];

    // preload K tile 0 into registers
    u32x4v kreg[8];
    #pragma unroll
    for (int p = 0; p < 8; ++p) {
        int f = p * 256 + t;
        int r = f >> 4, c = (f & 15) * 8;
        kreg[p] = *(const u32x4v*)(Kb + (size_t)(t0 + r) * 128 + c);
    }

    float num_acc[4][4], den_acc[4][4];
    #pragma unroll
    for (int i = 0; i < 4; ++i)
        #pragma unroll
        for (int r = 0; r < 4; ++r) { num_acc[i][r] = 0.f; den_acc[i][r] = 0.f; }

    for (int it = 0; it < 8; ++it) {
        __syncthreads();  // previous iter's LDS reads done (and Q staged, it=0)
        #pragma unroll
        for (int p = 0; p < 8; ++p) {
            int f = p * 256 + t;
            int r = f >> 4, c = (f & 15) * 8;
            *(u32x4v*)(&sK[r * LDQ + c]) = kreg[p];
        }
        __syncthreads();
        if (it < 7) {
            #pragma unroll
            for (int p = 0; p < 8; ++p) {
                int f = p * 256 + t;
                int r = f >> 4, c = (f & 15) * 8;
                kreg[p] = *(const u32x4v*)(Kb + (size_t)(t0 + (it + 1) * 128 + r) * 128 + c);
            }
        }

        floatx4 acc[4][4];
        #pragma unroll
        for (int i = 0; i < 4; ++i)
            #pragma unroll
            for (int j = 0; j < 4; ++j) acc[i][j] = {0.f, 0.f, 0.f, 0.f};

        #pragma unroll
        for (int kk = 0; kk < 4; ++kk) {
            bf16x8 afr[4], bfr[4];
            #pragma unroll
            for (int i = 0; i < 4; ++i)
                afr[i] = load_bf8(&sQ[(wr * 64 + i * 16 + m) * LDQ + kk * 32 + quad * 8]);
            #pragma unroll
            for (int j = 0; j < 4; ++j)
                bfr[j] = load_bf8(&sK[(wc * 64 + j * 16 + m) * LDQ + kk * 32 + quad * 8]);
            #pragma unroll
            for (int i = 0; i < 4; ++i)
                #pragma unroll
                for (int j = 0; j < 4; ++j)
                    acc[i][j] = __builtin_amdgcn_mfma_f32_16x16x32_bf16(afr[i], bfr[j], acc[i][j], 0, 0, 0);
        }

        #pragma unroll
        for (int j = 0; j < 4; ++j) {
            float vsv = sVS[it * 128 + wc * 64 + j * 16 + m];
            #pragma unroll
            for (int i = 0; i < 4; ++i)
                #pragma unroll
                for (int r = 0; r < 4; ++r) {
                    float p = __builtin_amdgcn_exp2f(acc[i][j][r] * SCALE_LOG2E);
                    den_acc[i][r] += p;
                    num_acc[i][r] += p * vsv;
                }
        }
    }

    #pragma unroll
    for (int i = 0; i < 4; ++i)
        #pragma unroll
        for (int r = 0; r < 4; ++r) {
            float n = num_acc[i][r], d = den_acc[i][r];
            #pragma unroll
            for (int mask = 1; mask <= 8; mask <<= 1) {
                n += __shfl_xor(n, mask, 64);
                d += __shfl_xor(d, mask, 64);
            }
            if ((lane & 15) == 0) {
                int row = q0 + wr * 64 + i * 16 + quad * 4 + r;
                atomicAdd(&num_g[row], n);
                atomicAdd(&den_g[row], d);
            }
        }
}

// ---------------------------------------------------------------------------
// Kernel D: gated = x1 * (1 - num/den). float4 grid-mapped, memory-bound.
// ---------------------------------------------------------------------------
__global__ void k_final(const float* __restrict__ x1,
                        const float* __restrict__ num_g,
                        const float* __restrict__ den_g,
                        float* __restrict__ outp) {
    int idx = blockIdx.x * 256 + threadIdx.x;  // float4 index, 192 per row
    int s = idx / 192;
    float4 v = *(const float4*)(x1 + (size_t)idx * 4);
    float g = 1.0f - num_g[s] / den_g[s];
    float4 rv;
    rv.x = v.x * g; rv.y = v.y * g; rv.z = v.z * g; rv.w = v.w * g;
    *(float4*)(outp + (size_t)idx * 4) = rv;
}

// ---------------------------------------------------------------------------
extern "C" void kernel_launch(void* const* d_in, const int* in_sizes, int n_in,
                              void* d_out, int out_size, void* d_ws, size_t ws_size,
                              hipStream_t stream) {
    const float* x1  = (const float*)d_in[0];
    const float* x2  = (const float*)d_in[1];
    const float* w_q = (const float*)d_in[2];
    const float* w_k = (const float*)d_in[3];
    const float* w_v = (const float*)d_in[4];
    const float* w_o = (const float*)d_in[5];
    float* outp = (float*)d_out;

    char* ws = (char*)d_ws;
    __hip_bfloat16* wq_bf = (__hip_bfloat16*)(ws + 0);        // 196608 B
    __hip_bfloat16* wk_bf = (__hip_bfloat16*)(ws + 196608);   // 196608 B
    float* c_buf          = (float*)(ws + 393216);            // 3072 B
    __hip_bfloat16* Qb    = (__hip_bfloat16*)(ws + 396288);   // 2 MB
    __hip_bfloat16* Kb    = (__hip_bfloat16*)(ws + 2493440);  // 2 MB
    float* vs_g           = (float*)(ws + 4590592);           // 32 KB
    float* num_g          = (float*)(ws + 4623360);           // 32 KB
    float* den_g          = (float*)(ws + 4656128);           // 32 KB

    hipMemsetAsync(num_g, 0, 8192 * sizeof(float), stream);
    hipMemsetAsync(den_g, 0, 8192 * sizeof(float), stream);

    k_prep<<<100, 256, 0, stream>>>(w_q, w_k, w_v, w_o, wq_bf, wk_bf, c_buf);
    k_qk<<<512, 256, 0, stream>>>(x1, x2, wq_bf, wk_bf, c_buf, Qb, Kb, vs_g);
    k_attn<<<512, 256, 0, stream>>>(Qb, Kb, vs_g, num_g, den_g);
    k_final<<<6144, 256, 0, stream>>>(x1, num_g, den_g, outp);
}